// Round 8
// baseline (300.664 us; speedup 1.0000x reference)
//
#include <hip/hip_runtime.h>
#include <hip/hip_bf16.h>

#define NOPT     5
#define NBATCH   100000
#define MTOT     (NOPT * NBATCH)   // 500000 rows
#define KDIM     600
#define NKS      19                // k-steps of 32 (last overlaps: k=568..599)
#define NT       5                 // n-tiles of 16 (75 -> 80, tail zero-padded)
#define ROWS     64                // rows per block
#define LDST     616               // LDS row stride in bf16 (1232 B, 16B-aligned)
#define F4_BLK   9600              // 64*600/4 f32x4 per block
#define F4_MAX   74999999          // 500000*600/4 - 1

typedef __bf16 bf16x8 __attribute__((ext_vector_type(8)));
typedef __bf16 bf16x4 __attribute__((ext_vector_type(4)));
typedef float  f32x4  __attribute__((ext_vector_type(4)));

__device__ __forceinline__ int kstart(int s) { return (s < 18) ? (s << 5) : 568; }

// Pre-transform W1 [75][600] fp32 -> bf16 image in exact MFMA B-fragment order:
// img[(s*5+t)*512 + l*8 + j] = W1[n=t*16+(l&15)][k=kstart(s)+(l>>4)*8+j], zeros for
// n>=75 and for the duplicated k range of the overlapping tail tile (s==18, kg==0).
__global__ void prep_w1(const float* __restrict__ W1, __bf16* __restrict__ img) {
    const int s  = blockIdx.x / NT;
    const int t  = blockIdx.x % NT;
    const int l  = threadIdx.x;            // 0..63
    const int kg = l >> 4;
    const int n  = t * 16 + (l & 15);
    const int ks = kstart(s);
    bf16x8 v;
#pragma unroll
    for (int j = 0; j < 8; ++j) {
        const int k = ks + kg * 8 + j;
        float f = 0.0f;
        if (n < 75 && !(s == 18 && kg == 0)) f = W1[n * KDIM + k];
        v[j] = (__bf16)f;
    }
    *(bf16x8*)(img + ((size_t)blockIdx.x * 64 + l) * 8) = v;
}

// Two-phase: P1 streams the block's CONTIGUOUS 150KB span of A sequentially
// (f32x4, perfectly coalesced+aligned), cvt to bf16, ds_write into a full
// [64][616] LDS tile. One __syncthreads. P2 runs all 19 K-steps from LDS
// (1 ds_read_b128/lane/step) with B fragments register-prefetched from the
// L2-resident img. No global_load_lds, no manual waitcnt, no races.
__global__ void __launch_bounds__(256, 2) ans_sel_kernel(
    const float* __restrict__ A,     // [500000][600] fp32
    const float* __restrict__ b1,    // [75]
    const float* __restrict__ W2,    // [75]
    const float* __restrict__ b2,    // [1]
    const __bf16* __restrict__ img,  // prepped W1 fragments
    float* __restrict__ out)         // [100000][5]
{
    __shared__ __bf16 At[ROWS * LDST];   // 78,848 B full A-tile (bf16)

    const int tid  = threadIdx.x;
    const int w    = tid >> 6;       // wave 0..3
    const int l    = tid & 63;
    const int kg   = l >> 4;
    const int ln16 = l & 15;
    const int row0 = blockIdx.x * ROWS;

    // ---------- Phase 1: sequential stream -> bf16 -> LDS ----------
    const f32x4* A4 = (const f32x4*)A;
    const long   bb = (long)blockIdx.x * F4_BLK;

#pragma unroll 2
    for (int g = 0; g < 10; ++g) {       // 10 groups x 4 slots = 40 >= 37.5
        int   i4c[4];
        f32x4 v[4];
#pragma unroll
        for (int j = 0; j < 4; ++j) {
            int i4 = tid + (g * 4 + j) * 256;
            i4c[j] = (i4 < F4_BLK - 1) ? i4 : (F4_BLK - 1);   // clamp: dup writes, same value
            long gi = bb + i4c[j];
            if (gi > F4_MAX) gi = F4_MAX;
            v[j] = A4[gi];
        }
#pragma unroll
        for (int j = 0; j < 4; ++j) {
            const int row = i4c[j] / 150;            // 150 f32x4 per row
            const int c4  = i4c[j] - row * 150;
            bf16x4 h;
            h[0] = (__bf16)v[j][0]; h[1] = (__bf16)v[j][1];
            h[2] = (__bf16)v[j][2]; h[3] = (__bf16)v[j][3];
            *(bf16x4*)&At[row * LDST + c4 * 4] = h;  // 8B store, 8B-aligned
        }
    }
    __syncthreads();

    // ---------- Phase 2: 19 K-steps from LDS + B reg-prefetch ----------
    f32x4 acc[NT];
#pragma unroll
    for (int t = 0; t < NT; ++t) acc[t] = (f32x4){0.f, 0.f, 0.f, 0.f};

    const __bf16* arow = &At[(w * 16 + ln16) * LDST];
    const __bf16* bp   = img + (size_t)l * 8;

    auto LDB = [&](int s, bf16x8& v0, bf16x8& v1, bf16x8& v2, bf16x8& v3, bf16x8& v4) {
        const __bf16* p = bp + (size_t)s * (NT * 512);
        v0 = *(const bf16x8*)(p);
        v1 = *(const bf16x8*)(p + 512);
        v2 = *(const bf16x8*)(p + 1024);
        v3 = *(const bf16x8*)(p + 1536);
        v4 = *(const bf16x8*)(p + 2048);
    };
    auto CMP = [&](int s, bf16x8 v0, bf16x8 v1, bf16x8 v2, bf16x8 v3, bf16x8 v4) {
        bf16x8 a = *(const bf16x8*)(arow + kstart(s) + kg * 8);  // 16B, aligned
        acc[0] = __builtin_amdgcn_mfma_f32_16x16x32_bf16(a, v0, acc[0], 0, 0, 0);
        acc[1] = __builtin_amdgcn_mfma_f32_16x16x32_bf16(a, v1, acc[1], 0, 0, 0);
        acc[2] = __builtin_amdgcn_mfma_f32_16x16x32_bf16(a, v2, acc[2], 0, 0, 0);
        acc[3] = __builtin_amdgcn_mfma_f32_16x16x32_bf16(a, v3, acc[3], 0, 0, 0);
        acc[4] = __builtin_amdgcn_mfma_f32_16x16x32_bf16(a, v4, acc[4], 0, 0, 0);
    };

    bf16x8 cb0, cb1, cb2, cb3, cb4, nb0, nb1, nb2, nb3, nb4;
    LDB(0, cb0, cb1, cb2, cb3, cb4);
#pragma unroll 1
    for (int s = 0; s < NKS - 1; ++s) {
        LDB(s + 1, nb0, nb1, nb2, nb3, nb4);
        CMP(s, cb0, cb1, cb2, cb3, cb4);
        cb0 = nb0; cb1 = nb1; cb2 = nb2; cb3 = nb3; cb4 = nb4;
    }
    CMP(NKS - 1, cb0, cb1, cb2, cb3, cb4);

    // Epilogue: C[row=(kg*4+q)][n=t*16+ln16] per lane (verified m89/m91 layout).
    float sq[4] = {0.f, 0.f, 0.f, 0.f};
#pragma unroll
    for (int t = 0; t < NT; ++t) {
        const int n = t * 16 + ln16;
        const float b1v = (n < 75) ? b1[n] : 0.f;
        const float w2v = (n < 75) ? W2[n] : 0.f;
#pragma unroll
        for (int q = 0; q < 4; ++q) {
            float h = acc[t][q] + b1v;
            h = h > 0.f ? h : 0.f;
            sq[q] += h * w2v;
        }
    }
#pragma unroll
    for (int m = 1; m < 16; m <<= 1) {
#pragma unroll
        for (int q = 0; q < 4; ++q) sq[q] += __shfl_xor(sq[q], m, 64);
    }
    if (ln16 == 0) {
        const float bb2 = b2[0];
#pragma unroll
        for (int q = 0; q < 4; ++q) {
            const int R = row0 + w * 16 + kg * 4 + q;   // global row = o*NBATCH + b
            if (R < MTOT) {
                const int o = R / NBATCH;
                const int b = R % NBATCH;
                out[(size_t)b * NOPT + o] = sq[q] + bb2;
            }
        }
    }
}

extern "C" void kernel_launch(void* const* d_in, const int* in_sizes, int n_in,
                              void* d_out, int out_size, void* d_ws, size_t ws_size,
                              hipStream_t stream) {
    const float* A  = (const float*)d_in[0];
    const float* W1 = (const float*)d_in[1];
    const float* b1 = (const float*)d_in[2];
    const float* W2 = (const float*)d_in[3];
    const float* b2 = (const float*)d_in[4];
    float* out = (float*)d_out;
    __bf16* img = (__bf16*)d_ws;     // needs 19*5*64*8*2 = 97280 B

    prep_w1<<<NKS * NT, 64, 0, stream>>>(W1, img);

    const int grid = (MTOT + ROWS - 1) / ROWS;   // 7813 blocks
    ans_sel_kernel<<<grid, 256, 0, stream>>>(A, b1, W2, b2, img, out);
}

// Round 9
// 295.512 us; speedup vs baseline: 1.0174x; 1.0174x over previous
//
#include <hip/hip_runtime.h>
#include <hip/hip_bf16.h>

#define NOPT    5
#define NBATCH  100000
#define MTOT    (NOPT * NBATCH)   // 500000 rows
#define KDIM    600
#define NT      5                 // n-tiles of 16 (75 -> 80, tail zero-padded)

typedef __bf16 bf16x8 __attribute__((ext_vector_type(8)));
typedef float  f32x4  __attribute__((ext_vector_type(4)));

__device__ __forceinline__ int kstart(int s) { return (s < 18) ? (s << 5) : 568; }

// Pre-transform W1 [75][600] fp32 -> bf16 image in exact MFMA B-fragment order:
// img[(s*5+t)*512 + l*8 + j] = W1[n=t*16+(l&15)][k=kstart(s)+(l>>4)*8+j], zeros for
// n>=75 and for the duplicated k range of the overlapping tail tile (s==18, kg==0).
// (s32 sub-tiles 0..17 cover k=0..575; 18 covers k=568..599 with 568..575 zeroed.)
__global__ void prep_w1(const float* __restrict__ W1, __bf16* __restrict__ img) {
    const int s  = blockIdx.x / NT;
    const int t  = blockIdx.x % NT;
    const int l  = threadIdx.x;            // 0..63
    const int kg = l >> 4;
    const int n  = t * 16 + (l & 15);
    const int ks = kstart(s);
    bf16x8 v;
#pragma unroll
    for (int j = 0; j < 8; ++j) {
        const int k = ks + kg * 8 + j;
        float f = 0.0f;
        if (n < 75 && !(s == 18 && kg == 0)) f = W1[n * KDIM + k];
        v[j] = (__bf16)f;
    }
    *(bf16x8*)(img + ((size_t)blockIdx.x * 64 + l) * 8) = v;
}

// BK=64: each k-step reads 256 CONSECUTIVE bytes per A-row (vs 128 in R1) to
// double DRAM page-visit length. A staged via global_load_lds (4 DMAs/wave of
// [4 rows][256B], source-XOR-swizzled, linear LDS dest). B consumed straight
// from the L2-resident img into registers each step (no LDS; the per-step
// __syncthreads drain retires everything, so no wait-coupling hazard).
// 9x64k steps + one 32k tail (reuses img sub-tile 18). Accumulation order is
// identical to the BK=32 versions (s32 = 0..18 in order).
__global__ void __launch_bounds__(256, 4) ans_sel_kernel(
    const float* __restrict__ A,     // [500000][600] fp32
    const float* __restrict__ b1,    // [75]
    const float* __restrict__ W2,    // [75]
    const float* __restrict__ b2,    // [1]
    const __bf16* __restrict__ img,  // prepped W1 fragments
    float* __restrict__ out)         // [100000][5]
{
    __shared__ f32x4 As[2][4][256];  // [buf][wave][16 rows x 16 chunks] = 32 KB

    const int tid  = threadIdx.x;
    const int w    = tid >> 6;       // wave 0..3
    const int l    = tid & 63;
    const int kg   = l >> 4;
    const int ln16 = l & 15;
    const int row0 = blockIdx.x * 64;

    // --- main-step DMA geometry: DMA d covers rows w*16+d*4 .. +3, 256B each.
    // lane l: row-in-dma = l>>4, chunk c = l&15. Source chunk swizzled c^(r&15)
    // so LDS slot [r*16 + p] holds global chunk (p ^ (r&15)). Dest linear.
    const int r16 = l >> 4;
    const int c16 = l & 15;
    const float* ap0; const float* ap1; const float* ap2; const float* ap3;
    {
        int r, gr;
        r = w * 16 + 0 * 4 + r16; gr = row0 + r; if (gr >= MTOT) gr = MTOT - 1;
        ap0 = A + (size_t)gr * KDIM + ((c16 ^ (r & 15)) << 2);
        r = w * 16 + 1 * 4 + r16; gr = row0 + r; if (gr >= MTOT) gr = MTOT - 1;
        ap1 = A + (size_t)gr * KDIM + ((c16 ^ (r & 15)) << 2);
        r = w * 16 + 2 * 4 + r16; gr = row0 + r; if (gr >= MTOT) gr = MTOT - 1;
        ap2 = A + (size_t)gr * KDIM + ((c16 ^ (r & 15)) << 2);
        r = w * 16 + 3 * 4 + r16; gr = row0 + r; if (gr >= MTOT) gr = MTOT - 1;
        ap3 = A + (size_t)gr * KDIM + ((c16 ^ (r & 15)) << 2);
    }
    // --- tail DMA geometry (BK=32 at k=568): DMA e covers rows w*16+e*8..+7,
    // 128B each; lane l: row = l>>3, chunk c8 = l&7, source chunk c8^(r&7).
    const int r8 = l >> 3;
    const int c8 = l & 7;
    const float* at0; const float* at1;
    {
        int r, gr;
        r = w * 16 + 0 * 8 + r8; gr = row0 + r; if (gr >= MTOT) gr = MTOT - 1;
        at0 = A + (size_t)gr * KDIM + 568 + ((c8 ^ (r & 7)) << 2);
        r = w * 16 + 1 * 8 + r8; gr = row0 + r; if (gr >= MTOT) gr = MTOT - 1;
        at1 = A + (size_t)gr * KDIM + 568 + ((c8 ^ (r & 7)) << 2);
    }

    auto stage64 = [&](int buf, int S) {
        const int k0 = S * 64;
        __builtin_amdgcn_global_load_lds(
            (const __attribute__((address_space(1))) void*)(ap0 + k0),
            (__attribute__((address_space(3))) void*)(&As[buf][w][0]),   16, 0, 0);
        __builtin_amdgcn_global_load_lds(
            (const __attribute__((address_space(1))) void*)(ap1 + k0),
            (__attribute__((address_space(3))) void*)(&As[buf][w][64]),  16, 0, 0);
        __builtin_amdgcn_global_load_lds(
            (const __attribute__((address_space(1))) void*)(ap2 + k0),
            (__attribute__((address_space(3))) void*)(&As[buf][w][128]), 16, 0, 0);
        __builtin_amdgcn_global_load_lds(
            (const __attribute__((address_space(1))) void*)(ap3 + k0),
            (__attribute__((address_space(3))) void*)(&As[buf][w][192]), 16, 0, 0);
    };
    auto stageTail = [&](int buf) {
        __builtin_amdgcn_global_load_lds(
            (const __attribute__((address_space(1))) void*)(at0),
            (__attribute__((address_space(3))) void*)(&As[buf][w][0]),   16, 0, 0);
        __builtin_amdgcn_global_load_lds(
            (const __attribute__((address_space(1))) void*)(at1),
            (__attribute__((address_space(3))) void*)(&As[buf][w][64]),  16, 0, 0);
    };

    f32x4 acc[NT];
#pragma unroll
    for (int t = 0; t < NT; ++t) acc[t] = (f32x4){0.f, 0.f, 0.f, 0.f};

    const __bf16* bp = img + (size_t)l * 8;

    // compute one 32-k sub-tile from LDS layout [16r][16c] at chunk offset o.
    auto sub64 = [&](int buf, int s32, int o) {
        const f32x4* base = &As[buf][w][ln16 * 16];
        f32x4 fa0 = base[(o    ) ^ ln16];
        f32x4 fa1 = base[(o + 1) ^ ln16];
        bf16x8 a;
        a[0] = (__bf16)fa0[0]; a[1] = (__bf16)fa0[1];
        a[2] = (__bf16)fa0[2]; a[3] = (__bf16)fa0[3];
        a[4] = (__bf16)fa1[0]; a[5] = (__bf16)fa1[1];
        a[6] = (__bf16)fa1[2]; a[7] = (__bf16)fa1[3];
        const __bf16* p = bp + (size_t)s32 * (NT * 512);
#pragma unroll
        for (int t = 0; t < NT; ++t) {
            bf16x8 b = *(const bf16x8*)(p + t * 512);
            acc[t] = __builtin_amdgcn_mfma_f32_16x16x32_bf16(a, b, acc[t], 0, 0, 0);
        }
    };
    auto compute64 = [&](int buf, int S) {
        sub64(buf, 2 * S,     kg * 2);        // kk=0: chunks 0..7
        sub64(buf, 2 * S + 1, 8 + kg * 2);    // kk=1: chunks 8..15
    };
    auto computeTail = [&](int buf) {        // [16r][8c] layout, s32=18
        const f32x4* base = &As[buf][w][ln16 * 8];
        const int o = kg * 2;
        f32x4 fa0 = base[(o    ) ^ (ln16 & 7)];
        f32x4 fa1 = base[(o + 1) ^ (ln16 & 7)];
        bf16x8 a;
        a[0] = (__bf16)fa0[0]; a[1] = (__bf16)fa0[1];
        a[2] = (__bf16)fa0[2]; a[3] = (__bf16)fa0[3];
        a[4] = (__bf16)fa1[0]; a[5] = (__bf16)fa1[1];
        a[6] = (__bf16)fa1[2]; a[7] = (__bf16)fa1[3];
        const __bf16* p = bp + (size_t)18 * (NT * 512);
#pragma unroll
        for (int t = 0; t < NT; ++t) {
            bf16x8 b = *(const bf16x8*)(p + t * 512);
            acc[t] = __builtin_amdgcn_mfma_f32_16x16x32_bf16(a, b, acc[t], 0, 0, 0);
        }
    };

    // 2-phase (R1-proven): stage next, compute current, barrier (full drain).
    stage64(0, 0);
    __syncthreads();
    int buf = 0;
#pragma unroll 1
    for (int S = 0; S < 9; ++S) {
        if (S < 8) stage64(buf ^ 1, S + 1);
        else       stageTail(buf ^ 1);
        compute64(buf, S);
        __syncthreads();
        buf ^= 1;
    }
    computeTail(buf);

    // Epilogue: C[row=(kg*4+q)][n=t*16+ln16] per lane (verified m89/m91 layout).
    float sq[4] = {0.f, 0.f, 0.f, 0.f};
#pragma unroll
    for (int t = 0; t < NT; ++t) {
        const int n = t * 16 + ln16;
        const float b1v = (n < 75) ? b1[n] : 0.f;
        const float w2v = (n < 75) ? W2[n] : 0.f;
#pragma unroll
        for (int q = 0; q < 4; ++q) {
            float h = acc[t][q] + b1v;
            h = h > 0.f ? h : 0.f;
            sq[q] += h * w2v;
        }
    }
#pragma unroll
    for (int m = 1; m < 16; m <<= 1) {
#pragma unroll
        for (int q = 0; q < 4; ++q) sq[q] += __shfl_xor(sq[q], m, 64);
    }
    if (ln16 == 0) {
        const float bb = b2[0];
#pragma unroll
        for (int q = 0; q < 4; ++q) {
            const int R = row0 + w * 16 + kg * 4 + q;   // global row = o*NBATCH + b
            if (R < MTOT) {
                const int o = R / NBATCH;
                const int b = R % NBATCH;
                out[(size_t)b * NOPT + o] = sq[q] + bb;
            }
        }
    }
}

extern "C" void kernel_launch(void* const* d_in, const int* in_sizes, int n_in,
                              void* d_out, int out_size, void* d_ws, size_t ws_size,
                              hipStream_t stream) {
    const float* A  = (const float*)d_in[0];
    const float* W1 = (const float*)d_in[1];
    const float* b1 = (const float*)d_in[2];
    const float* W2 = (const float*)d_in[3];
    const float* b2 = (const float*)d_in[4];
    float* out = (float*)d_out;
    __bf16* img = (__bf16*)d_ws;     // needs 19*5*64*8*2 = 97280 B

    prep_w1<<<19 * NT, 64, 0, stream>>>(W1, img);

    const int grid = (MTOT + 63) / 64;   // 7813 blocks, 4 waves each
    ans_sel_kernel<<<grid, 256, 0, stream>>>(A, b1, W2, b2, img, out);
}